// Round 1
// baseline (5360.247 us; speedup 1.0000x reference)
//
#include <hip/hip_runtime.h>

static constexpr int BN = 8;
static constexpr int CX = 128;   // x input channels
static constexpr int CO = 128;   // output channels
static constexpr int HH = 64;
static constexpr int WW = 64;
static constexpr int KT = 121;   // 11*11
static constexpr int NPIX = HH * WW;        // 4096
static constexpr int TOTPIX = BN * NPIX;    // 32768
static constexpr int WPART = CX * KT * CO;  // 1982464

// ---------------------------------------------------------------------------
// K1: transpose W [co][256][11][11] -> WxT [ci][k][co] (ci<128) and
//     WzT [cz][k][co] (input channels 128..255)
// ---------------------------------------------------------------------------
__global__ __launch_bounds__(256) void k_wt(const float* __restrict__ W,
                                            float* __restrict__ WxT,
                                            float* __restrict__ WzT) {
  int id = blockIdx.x * 256 + threadIdx.x;
  if (id >= 2 * WPART) return;
  int part = id / WPART;
  int r = id - part * WPART;
  int co = r & 127;
  int rk = r >> 7;          // ci*121 + k
  int k = rk % KT;
  int ci = rk / KT;
  float v = W[(co * 256 + part * 128 + ci) * KT + k];
  if (part) WzT[r] = v;
  else      WxT[r] = v;
}

// ---------------------------------------------------------------------------
// K2: base = conv(x, W[:, :128])  SAME pad 5, f64 accumulation.
// Block tile: 1 b, 4 h, 32 w, 32 co.  Thread tile: 1 h, 4 w, 4 co.
// Grid: 2(w) * 16(h) * 8(b) * 4(co) = 1024 blocks, 256 threads.
// ---------------------------------------------------------------------------
__global__ __launch_bounds__(256) void k_conv(const float* __restrict__ x,
                                              const float* __restrict__ WxT,
                                              double* __restrict__ base) {
  int blk = blockIdx.x;
  int cog = blk & 3;
  int b   = (blk >> 2) & 7;
  int ht  = (blk >> 5) & 15;
  int wt  = (blk >> 9) & 1;
  int H0 = ht * 4, W0 = wt * 32, CO0 = cog * 32;

  int tid = threadIdx.x;
  int coq = tid & 7;          // co = CO0 + coq*4 + c
  int wq  = (tid >> 3) & 7;   // w  = W0 + wq*4 + p
  int th  = tid >> 6;         // h  = H0 + th

  __shared__ float xs[2 * 14 * 44];    // [ci][row 14][w 44 (42 used, padded)]
  __shared__ float wsl[2 * 121 * 32];  // [ci][k][co32]

  double acc[4][4];
#pragma unroll
  for (int p = 0; p < 4; ++p)
#pragma unroll
    for (int c = 0; c < 4; ++c) acc[p][c] = 0.0;

  for (int cc = 0; cc < 64; ++cc) {   // ci chunks of 2
    // --- stage x patch: rows H0-5..H0+8, cols W0-5..W0+36 (zero-padded) ---
    for (int e = tid; e < 2 * 14 * 44; e += 256) {
      int ci = e / (14 * 44);
      int rr = e - ci * (14 * 44);
      int r  = rr / 44;
      int w  = rr - r * 44;
      float v = 0.f;
      int gh = H0 - 5 + r;
      int gw = W0 - 5 + w;
      if (w < 42 && (unsigned)gh < 64u && (unsigned)gw < 64u) {
        int cig = cc * 2 + ci;
        v = x[((b * CX + cig) * HH + gh) * WW + gw];
      }
      xs[e] = v;
    }
    // --- stage weights: [2ci][121][32co] as float4 ---
    for (int f = tid; f < 1936; f += 256) {
      int seg = f >> 3;          // ci*121 + k
      int off = f & 7;
      int ci = seg / 121;
      int k  = seg - ci * 121;
      const float4 src = *reinterpret_cast<const float4*>(
          &WxT[((cc * 2 + ci) * 121 + k) * 128 + CO0 + off * 4]);
      *reinterpret_cast<float4*>(&wsl[(ci * 121 + k) * 32 + off * 4]) = src;
    }
    __syncthreads();

    for (int ci = 0; ci < 2; ++ci) {
      for (int ki = 0; ki < 11; ++ki) {
        int row = th + ki;
        const float4* xr =
            reinterpret_cast<const float4*>(&xs[(ci * 14 + row) * 44 + wq * 4]);
        float4 x0 = xr[0], x1 = xr[1], x2 = xr[2], x3 = xr[3];
        double xd[16];
        xd[0] = x0.x; xd[1] = x0.y; xd[2]  = x0.z; xd[3]  = x0.w;
        xd[4] = x1.x; xd[5] = x1.y; xd[6]  = x1.z; xd[7]  = x1.w;
        xd[8] = x2.x; xd[9] = x2.y; xd[10] = x2.z; xd[11] = x2.w;
        xd[12] = x3.x; xd[13] = x3.y; xd[14] = x3.z; xd[15] = x3.w;
#pragma unroll
        for (int kj = 0; kj < 11; ++kj) {
          float4 wv = *reinterpret_cast<const float4*>(
              &wsl[(ci * 121 + ki * 11 + kj) * 32 + coq * 4]);
          double w0 = wv.x, w1 = wv.y, w2 = wv.z, w3 = wv.w;
#pragma unroll
          for (int p = 0; p < 4; ++p) {
            double xv = xd[p + kj];
            acc[p][0] = fma(xv, w0, acc[p][0]);
            acc[p][1] = fma(xv, w1, acc[p][1]);
            acc[p][2] = fma(xv, w2, acc[p][2]);
            acc[p][3] = fma(xv, w3, acc[p][3]);
          }
        }
      }
    }
    __syncthreads();
  }

  int h = H0 + th;
#pragma unroll
  for (int c = 0; c < 4; ++c) {
    int co = CO0 + coq * 4 + c;
    double* dst = &base[((b * CO + co) * HH + h) * WW + W0 + wq * 4];
#pragma unroll
    for (int p = 0; p < 4; ++p) dst[p] = acc[p][c];
  }
}

// ---------------------------------------------------------------------------
// K3: one block per pixel (128 threads = 128 output channels).
// realy = base + lateral_gather - bias; t>0: 0.5*realy + 0.5*z_prev
// WTA over channels -> z, features, winner index, rate/change counts.
// ---------------------------------------------------------------------------
__global__ __launch_bounds__(128) void k_step(
    const double* __restrict__ base, const float* __restrict__ WzT,
    const double* __restrict__ bias, const unsigned int* __restrict__ widxPrev,
    unsigned int* __restrict__ widxCur, float* __restrict__ feat,
    unsigned int* __restrict__ counts, unsigned int* __restrict__ chg, int t) {
  int pix = blockIdx.x;
  int b  = pix >> 12;
  int hw = pix & 4095;
  int h = hw >> 6, w = hw & 63;
  int co = threadIdx.x;

  __shared__ int nbr[121];
  __shared__ double red[2];
  __shared__ unsigned long long bal[2];

  if (t > 0 && co < 121) {
    int ki = co / 11, kj = co - ki * 11;
    int nh = h + ki - 5, nw = w + kj - 5;
    int c = 255;
    if ((unsigned)nh < 64u && (unsigned)nw < 64u)
      c = (int)widxPrev[b * 4096 + nh * 64 + nw];
    nbr[co] = c;
  }
  __syncthreads();

  double realy = base[((b * 128 + co) * 64 + h) * 64 + w];
  if (t > 0) {
    double a = 0.0;
    for (int k = 0; k < 121; ++k) {
      int c = nbr[k];                  // wave-uniform
      if (c < 128) a += (double)WzT[(c * 121 + k) * 128 + co];
    }
    realy += a;
  }
  realy -= bias[co];

  float zp = 0.f;
  if (t > 0) {
    zp = feat[(size_t)(b * 6 + (t - 1)) * 524288 + co * 4096 + hw];
    realy = 0.5 * realy + 0.5 * (double)zp;
  }

  // max over 128 channels
  double m = realy;
#pragma unroll
  for (int s = 1; s < 64; s <<= 1) m = fmax(m, __shfl_xor(m, s, 64));
  int wid = co >> 6;
  if ((co & 63) == 0) red[wid] = m;
  __syncthreads();
  double thr = fmax(red[0], red[1]);

  bool z = (realy == thr) && (realy > 0.0);
  feat[(size_t)(b * 6 + t) * 524288 + co * 4096 + hw] = z ? 1.0f : 0.0f;

  unsigned long long mb = __ballot(z);
  bool dif = ((z ? 1.0f : 0.0f) != zp);
  unsigned long long db = __ballot(dif);
  if ((co & 63) == 0) bal[wid] = mb;
  __syncthreads();

  if (co == 0) {
    unsigned long long b0 = bal[0], b1 = bal[1];
    int wi = 255;
    if (b0) wi = __ffsll((unsigned long long)b0) - 1;
    else if (b1) wi = 64 + __ffsll((unsigned long long)b1) - 1;
    widxCur[pix] = (unsigned int)wi;
  }
  if (z) atomicAdd(&counts[t * 128 + co], 1u);
  if ((co & 63) == 0 && db) atomicAdd(&chg[t], (unsigned int)__popcll(db));
}

// ---------------------------------------------------------------------------
// K4: bias update + changes[t]
// ---------------------------------------------------------------------------
__global__ __launch_bounds__(128) void k_fin(double* __restrict__ bias,
                                             float* __restrict__ outChanges,
                                             const unsigned int* __restrict__ counts,
                                             const unsigned int* __restrict__ chg,
                                             int t) {
  int co = threadIdx.x;
  double rate = (double)counts[t * 128 + co] * (1.0 / 32768.0);
  bias[co] += 0.05 * (rate - 1.0 / 128.0);
  if (co == 0) outChanges[t] = (float)((double)chg[t] * (1.0 / 8388608.0));
}

// ---------------------------------------------------------------------------
extern "C" void kernel_launch(void* const* d_in, const int* in_sizes, int n_in,
                              void* d_out, int out_size, void* d_ws, size_t ws_size,
                              hipStream_t stream) {
  const float* x = (const float*)d_in[0];
  const float* W = (const float*)d_in[1];
  float* out = (float*)d_out;

  char* ws = (char*)d_ws;
  float* WxT = (float*)ws;                               // 7,929,856 B
  float* WzT = (float*)(ws + 7929856);                   // 7,929,856 B
  double* base = (double*)(ws + 2 * 7929856);            // 33,554,432 B
  char* p = ws + 2 * 7929856 + 33554432;
  double* bias = (double*)p;           p += 1024;        // 128 f64
  unsigned int* counts = (unsigned int*)p; p += 6 * 128 * 4;  // 3072
  unsigned int* chg = (unsigned int*)p;    p += 256;
  unsigned int* widx0 = (unsigned int*)p;  p += TOTPIX * 4;
  unsigned int* widx1 = (unsigned int*)p;

  // zero bias + counts + chg (contiguous 4352 bytes)
  hipMemsetAsync(bias, 0, 4352, stream);

  k_wt<<<(2 * WPART + 255) / 256, 256, 0, stream>>>(W, WxT, WzT);
  k_conv<<<1024, 256, 0, stream>>>(x, WxT, base);

  float* feat = out + 6;
  for (int t = 0; t < 6; ++t) {
    unsigned int* wp = (t & 1) ? widx1 : widx0;
    unsigned int* wc = (t & 1) ? widx0 : widx1;
    k_step<<<TOTPIX, 128, 0, stream>>>(base, WzT, bias, wp, wc, feat, counts,
                                       chg, t);
    k_fin<<<1, 128, 0, stream>>>(bias, out, counts, chg, t);
  }
}

// Round 2
// 4998.499 us; speedup vs baseline: 1.0724x; 1.0724x over previous
//
#include <hip/hip_runtime.h>

static constexpr int BN = 8;
static constexpr int CX = 128;   // x input channels
static constexpr int CO = 128;   // output channels
static constexpr int HH = 64;
static constexpr int WW = 64;
static constexpr int KT = 121;   // 11*11
static constexpr int NPIX = HH * WW;        // 4096
static constexpr int TOTPIX = BN * NPIX;    // 32768
static constexpr int WPART = CX * KT * CO;  // 1982464

// ---------------------------------------------------------------------------
// K1: transpose W [co][256][11][11] -> WxT [ci][k][co] (ci<128) and
//     WzT [cz][k][co] (input channels 128..255)
// ---------------------------------------------------------------------------
__global__ __launch_bounds__(256) void k_wt(const float* __restrict__ W,
                                            float* __restrict__ WxT,
                                            float* __restrict__ WzT) {
  int id = blockIdx.x * 256 + threadIdx.x;
  if (id >= 2 * WPART) return;
  int part = id / WPART;
  int r = id - part * WPART;
  int co = r & 127;
  int rk = r >> 7;          // ci*121 + k
  int k = rk % KT;
  int ci = rk / KT;
  float v = W[(co * 256 + part * 128 + ci) * KT + k];
  if (part) WzT[r] = v;
  else      WxT[r] = v;
}

// ---------------------------------------------------------------------------
// K2: base = conv(x, W[:, :128])  SAME pad 5, f64 accumulation.
// Block tile: 1 b, 8 h, 32 w, 32 co.  Thread tile: 1 h, 8 w, 4 co.
// Grid: 4(co) * 2(w) * 8(h) * 8(b) = 512 blocks, 256 threads.
// LDS: x staged as f64 (converted once at staging), weights f32.
// Inner loop per (ci,ki): 352 v_fma_f64 + 44 cvt + 9+11 ds_read_b128.
// ---------------------------------------------------------------------------
__global__ __launch_bounds__(256) void k_conv(const float* __restrict__ x,
                                              const float* __restrict__ WxT,
                                              double* __restrict__ base) {
  int blk = blockIdx.x;
  int cog = blk & 3;
  int wt  = (blk >> 2) & 1;
  int ht  = (blk >> 3) & 7;
  int b   = blk >> 6;
  int H0 = ht * 8, W0 = wt * 32, CO0 = cog * 32;

  int tid = threadIdx.x;
  int coq = tid & 7;          // co = CO0 + coq*4 + c
  int wq  = (tid >> 3) & 3;   // w  = W0 + wq*8 + p, p<8
  int th  = tid >> 5;         // h  = H0 + th, th<8

  // xs: [ci 2][row 18][col 44 (42 valid, pad 2)] as f64
  // wsl: [ci 2][k 121][co 32] as f32
  __shared__ double xs[2 * 18 * 44];    // 12672 B
  __shared__ float wsl[2 * 121 * 32];   // 30976 B

  double acc[8][4];
#pragma unroll
  for (int p = 0; p < 8; ++p)
#pragma unroll
    for (int c = 0; c < 4; ++c) acc[p][c] = 0.0;

  for (int cc = 0; cc < 64; ++cc) {   // ci chunks of 2
    // --- stage x patch rows H0-5..H0+12, cols W0-5..W0+36, f32->f64 ---
    for (int e = tid; e < 2 * 18 * 44; e += 256) {
      int ci = e / (18 * 44);
      int rr = e - ci * (18 * 44);
      int r  = rr / 44;
      int w  = rr - r * 44;
      double v = 0.0;
      int gh = H0 - 5 + r;
      int gw = W0 - 5 + w;
      if (w < 42 && (unsigned)gh < 64u && (unsigned)gw < 64u) {
        int cig = cc * 2 + ci;
        v = (double)x[((b * CX + cig) * HH + gh) * WW + gw];
      }
      xs[e] = v;
    }
    // --- stage weights: [2ci][121][32co] as float4 ---
    for (int f = tid; f < 1936; f += 256) {
      int seg = f >> 3;          // ci*121 + k
      int off = f & 7;
      int ci = seg / 121;
      int k  = seg - ci * 121;
      const float4 src = *reinterpret_cast<const float4*>(
          &WxT[((cc * 2 + ci) * 121 + k) * 128 + CO0 + off * 4]);
      *reinterpret_cast<float4*>(&wsl[(ci * 121 + k) * 32 + off * 4]) = src;
    }
    __syncthreads();

    for (int ci = 0; ci < 2; ++ci) {
      for (int ki = 0; ki < 11; ++ki) {
        int row = th + ki;
        const double2* xr = reinterpret_cast<const double2*>(
            &xs[(ci * 18 + row) * 44 + wq * 8]);
        double xd[18];
#pragma unroll
        for (int j = 0; j < 9; ++j) {
          double2 tv = xr[j];
          xd[2 * j] = tv.x;
          xd[2 * j + 1] = tv.y;
        }
#pragma unroll
        for (int kj = 0; kj < 11; ++kj) {
          float4 wv = *reinterpret_cast<const float4*>(
              &wsl[(ci * 121 + ki * 11 + kj) * 32 + coq * 4]);
          double w0 = wv.x, w1 = wv.y, w2 = wv.z, w3 = wv.w;
#pragma unroll
          for (int p = 0; p < 8; ++p) {
            double xv = xd[p + kj];
            acc[p][0] = fma(xv, w0, acc[p][0]);
            acc[p][1] = fma(xv, w1, acc[p][1]);
            acc[p][2] = fma(xv, w2, acc[p][2]);
            acc[p][3] = fma(xv, w3, acc[p][3]);
          }
        }
      }
    }
    __syncthreads();
  }

  int h = H0 + th;
#pragma unroll
  for (int c = 0; c < 4; ++c) {
    int co = CO0 + coq * 4 + c;
    double* dst = &base[((b * CO + co) * HH + h) * WW + W0 + wq * 8];
#pragma unroll
    for (int p = 0; p < 8; ++p) dst[p] = acc[p][c];
  }
}

// ---------------------------------------------------------------------------
// K3: one block per pixel (128 threads = 128 output channels).
// realy = base + lateral_gather - bias; t>0: 0.5*realy + 0.5*z_prev
// WTA over channels -> z, features, winner index, rate/change counts.
// ---------------------------------------------------------------------------
__global__ __launch_bounds__(128) void k_step(
    const double* __restrict__ base, const float* __restrict__ WzT,
    const double* __restrict__ bias, const unsigned int* __restrict__ widxPrev,
    unsigned int* __restrict__ widxCur, float* __restrict__ feat,
    unsigned int* __restrict__ counts, unsigned int* __restrict__ chg, int t) {
  int pix = blockIdx.x;
  int b  = pix >> 12;
  int hw = pix & 4095;
  int h = hw >> 6, w = hw & 63;
  int co = threadIdx.x;

  __shared__ int nbr[121];
  __shared__ double red[2];
  __shared__ unsigned long long bal[2];

  if (t > 0 && co < 121) {
    int ki = co / 11, kj = co - ki * 11;
    int nh = h + ki - 5, nw = w + kj - 5;
    int c = 255;
    if ((unsigned)nh < 64u && (unsigned)nw < 64u)
      c = (int)widxPrev[b * 4096 + nh * 64 + nw];
    nbr[co] = c;
  }
  __syncthreads();

  double realy = base[((b * 128 + co) * 64 + h) * 64 + w];
  if (t > 0) {
    double a = 0.0;
    for (int k = 0; k < 121; ++k) {
      int c = nbr[k];                  // wave-uniform
      if (c < 128) a += (double)WzT[(c * 121 + k) * 128 + co];
    }
    realy += a;
  }
  realy -= bias[co];

  float zp = 0.f;
  if (t > 0) {
    zp = feat[(size_t)(b * 6 + (t - 1)) * 524288 + co * 4096 + hw];
    realy = 0.5 * realy + 0.5 * (double)zp;
  }

  // max over 128 channels
  double m = realy;
#pragma unroll
  for (int s = 1; s < 64; s <<= 1) m = fmax(m, __shfl_xor(m, s, 64));
  int wid = co >> 6;
  if ((co & 63) == 0) red[wid] = m;
  __syncthreads();
  double thr = fmax(red[0], red[1]);

  bool z = (realy == thr) && (realy > 0.0);
  feat[(size_t)(b * 6 + t) * 524288 + co * 4096 + hw] = z ? 1.0f : 0.0f;

  unsigned long long mb = __ballot(z);
  bool dif = ((z ? 1.0f : 0.0f) != zp);
  unsigned long long db = __ballot(dif);
  if ((co & 63) == 0) bal[wid] = mb;
  __syncthreads();

  if (co == 0) {
    unsigned long long b0 = bal[0], b1 = bal[1];
    int wi = 255;
    if (b0) wi = __ffsll((unsigned long long)b0) - 1;
    else if (b1) wi = 64 + __ffsll((unsigned long long)b1) - 1;
    widxCur[pix] = (unsigned int)wi;
  }
  if (z) atomicAdd(&counts[t * 128 + co], 1u);
  if ((co & 63) == 0 && db) atomicAdd(&chg[t], (unsigned int)__popcll(db));
}

// ---------------------------------------------------------------------------
// K4: bias update + changes[t]
// ---------------------------------------------------------------------------
__global__ __launch_bounds__(128) void k_fin(double* __restrict__ bias,
                                             float* __restrict__ outChanges,
                                             const unsigned int* __restrict__ counts,
                                             const unsigned int* __restrict__ chg,
                                             int t) {
  int co = threadIdx.x;
  double rate = (double)counts[t * 128 + co] * (1.0 / 32768.0);
  bias[co] += 0.05 * (rate - 1.0 / 128.0);
  if (co == 0) outChanges[t] = (float)((double)chg[t] * (1.0 / 8388608.0));
}

// ---------------------------------------------------------------------------
extern "C" void kernel_launch(void* const* d_in, const int* in_sizes, int n_in,
                              void* d_out, int out_size, void* d_ws, size_t ws_size,
                              hipStream_t stream) {
  const float* x = (const float*)d_in[0];
  const float* W = (const float*)d_in[1];
  float* out = (float*)d_out;

  char* ws = (char*)d_ws;
  float* WxT = (float*)ws;                               // 7,929,856 B
  float* WzT = (float*)(ws + 7929856);                   // 7,929,856 B
  double* base = (double*)(ws + 2 * 7929856);            // 33,554,432 B
  char* p = ws + 2 * 7929856 + 33554432;
  double* bias = (double*)p;           p += 1024;        // 128 f64
  unsigned int* counts = (unsigned int*)p; p += 6 * 128 * 4;  // 3072
  unsigned int* chg = (unsigned int*)p;    p += 256;
  unsigned int* widx0 = (unsigned int*)p;  p += TOTPIX * 4;
  unsigned int* widx1 = (unsigned int*)p;

  // zero bias + counts + chg (contiguous 4352 bytes)
  hipMemsetAsync(bias, 0, 4352, stream);

  k_wt<<<(2 * WPART + 255) / 256, 256, 0, stream>>>(W, WxT, WzT);
  k_conv<<<512, 256, 0, stream>>>(x, WxT, base);

  float* feat = out + 6;
  for (int t = 0; t < 6; ++t) {
    unsigned int* wp = (t & 1) ? widx1 : widx0;
    unsigned int* wc = (t & 1) ? widx0 : widx1;
    k_step<<<TOTPIX, 128, 0, stream>>>(base, WzT, bias, wp, wc, feat, counts,
                                       chg, t);
    k_fin<<<1, 128, 0, stream>>>(bias, out, counts, chg, t);
  }
}

// Round 3
// 4753.190 us; speedup vs baseline: 1.1277x; 1.0516x over previous
//
#include <hip/hip_runtime.h>

static constexpr int BN = 8;
static constexpr int CX = 128;   // x input channels
static constexpr int CO = 128;   // output channels
static constexpr int HH = 64;
static constexpr int WW = 64;
static constexpr int KT = 121;   // 11*11
static constexpr int NPIX = HH * WW;        // 4096
static constexpr int TOTPIX = BN * NPIX;    // 32768
static constexpr int WPART = CX * KT * CO;  // 1982464

// ---------------------------------------------------------------------------
// K1: transpose W [co][256][11][11] -> WxT [ci][k][co] (ci<128) and
//     WzT [cz][k][co] (input channels 128..255)
// ---------------------------------------------------------------------------
__global__ __launch_bounds__(256) void k_wt(const float* __restrict__ W,
                                            float* __restrict__ WxT,
                                            float* __restrict__ WzT) {
  int id = blockIdx.x * 256 + threadIdx.x;
  if (id >= 2 * WPART) return;
  int part = id / WPART;
  int r = id - part * WPART;
  int co = r & 127;
  int rk = r >> 7;          // ci*121 + k
  int k = rk % KT;
  int ci = rk / KT;
  float v = W[(co * 256 + part * 128 + ci) * KT + k];
  if (part) WzT[r] = v;
  else      WxT[r] = v;
}

// ---------------------------------------------------------------------------
// K2: base = conv(x, W[:, :128])  SAME pad 5, f64 accumulation.
// Block tile: 1 b, 4 h, 32 w, 32 co.  Thread tile: 1 h, 8 w, 2 co.
// Grid: 4(co) * 2(w) * 16(h) * 8(b) = 1024 blocks = 4 blocks/CU, 256 thr.
// LDS 35,904 B -> 4 blocks/CU. Weights AND x staged as f64 (cvt at stage).
// Inner loop per ki: 11 kj * 16 = 176 v_fma_f64 + 9 (x) + 11 (w) ds_read_b128,
// zero in-loop cvt.
// ---------------------------------------------------------------------------
__global__ __launch_bounds__(256, 4) void k_conv(const float* __restrict__ x,
                                                 const float* __restrict__ WxT,
                                                 double* __restrict__ base) {
  int blk = blockIdx.x;
  int cog = blk & 3;
  int wt  = (blk >> 2) & 1;
  int ht  = (blk >> 3) & 15;
  int b   = blk >> 7;
  int H0 = ht * 4, W0 = wt * 32, CO0 = cog * 32;

  int tid = threadIdx.x;
  int coq = tid & 15;          // co = CO0 + coq*2 + c, c<2
  int wq  = (tid >> 4) & 3;    // w  = W0 + wq*8 + p,  p<8
  int th  = tid >> 6;          // h  = H0 + th,        th<4

  // xs: [row 14][col 44 (42 valid, pad 2)] f64   = 4,928 B
  // wsl: [k 121][co 32] f64                      = 30,976 B
  __shared__ double xs[14 * 44];
  __shared__ double wsl[121 * 32];

  double acc[8][2];
#pragma unroll
  for (int p = 0; p < 8; ++p) {
    acc[p][0] = 0.0;
    acc[p][1] = 0.0;
  }

  for (int ci = 0; ci < CX; ++ci) {
    // --- stage x patch rows H0-5..H0+8, cols W0-5..W0+36, f32->f64 ---
    for (int e = tid; e < 14 * 44; e += 256) {
      int r = e / 44;
      int w = e - r * 44;
      double v = 0.0;
      int gh = H0 - 5 + r;
      int gw = W0 - 5 + w;
      if (w < 42 && (unsigned)gh < 64u && (unsigned)gw < 64u)
        v = (double)x[((b * CX + ci) * HH + gh) * WW + gw];
      xs[e] = v;
    }
    // --- stage weights [121][32co] f32 -> f64 ---
    for (int f = tid; f < 968; f += 256) {   // 121*32/4 float4 chunks
      int k   = f >> 3;
      int off = f & 7;
      float4 src = *reinterpret_cast<const float4*>(
          &WxT[(ci * KT + k) * 128 + CO0 + off * 4]);
      double2 lo, hi;
      lo.x = (double)src.x; lo.y = (double)src.y;
      hi.x = (double)src.z; hi.y = (double)src.w;
      *reinterpret_cast<double2*>(&wsl[k * 32 + off * 4])     = lo;
      *reinterpret_cast<double2*>(&wsl[k * 32 + off * 4 + 2]) = hi;
    }
    __syncthreads();

#pragma unroll
    for (int ki = 0; ki < 11; ++ki) {
      int row = th + ki;
      const double2* xr =
          reinterpret_cast<const double2*>(&xs[row * 44 + wq * 8]);
      double xd[18];
#pragma unroll
      for (int j = 0; j < 9; ++j) {
        double2 tv = xr[j];
        xd[2 * j]     = tv.x;
        xd[2 * j + 1] = tv.y;
      }
#pragma unroll
      for (int kj = 0; kj < 11; ++kj) {
        double2 wv = *reinterpret_cast<const double2*>(
            &wsl[(ki * 11 + kj) * 32 + coq * 2]);
#pragma unroll
        for (int p = 0; p < 8; ++p) {
          double xv = xd[p + kj];
          acc[p][0] = fma(xv, wv.x, acc[p][0]);
          acc[p][1] = fma(xv, wv.y, acc[p][1]);
        }
      }
    }
    __syncthreads();
  }

  int h = H0 + th;
#pragma unroll
  for (int c = 0; c < 2; ++c) {
    int co = CO0 + coq * 2 + c;
    double* dst = &base[((b * CO + co) * HH + h) * WW + W0 + wq * 8];
#pragma unroll
    for (int p = 0; p < 8; ++p) dst[p] = acc[p][c];
  }
}

// ---------------------------------------------------------------------------
// K3: one block per pixel (128 threads = 128 output channels).
// realy = base + lateral_gather - bias; t>0: 0.5*realy + 0.5*z_prev
// WTA over channels -> z, features, winner index, rate/change counts.
// ---------------------------------------------------------------------------
__global__ __launch_bounds__(128) void k_step(
    const double* __restrict__ base, const float* __restrict__ WzT,
    const double* __restrict__ bias, const unsigned int* __restrict__ widxPrev,
    unsigned int* __restrict__ widxCur, float* __restrict__ feat,
    unsigned int* __restrict__ counts, unsigned int* __restrict__ chg, int t) {
  int pix = blockIdx.x;
  int b  = pix >> 12;
  int hw = pix & 4095;
  int h = hw >> 6, w = hw & 63;
  int co = threadIdx.x;

  __shared__ int nbr[121];
  __shared__ double red[2];
  __shared__ unsigned long long bal[2];

  if (t > 0 && co < 121) {
    int ki = co / 11, kj = co - ki * 11;
    int nh = h + ki - 5, nw = w + kj - 5;
    int c = 255;
    if ((unsigned)nh < 64u && (unsigned)nw < 64u)
      c = (int)widxPrev[b * 4096 + nh * 64 + nw];
    nbr[co] = c;
  }
  __syncthreads();

  double realy = base[((b * 128 + co) * 64 + h) * 64 + w];
  if (t > 0) {
    // 4 partial sums break the serial f64 dependence chain
    double a0 = 0.0, a1 = 0.0, a2 = 0.0, a3 = 0.0;
#pragma unroll 2
    for (int k = 0; k < 120; k += 4) {
      int c0 = nbr[k], c1 = nbr[k + 1], c2 = nbr[k + 2], c3 = nbr[k + 3];
      if (c0 < 128) a0 += (double)WzT[(c0 * KT + k) * 128 + co];
      if (c1 < 128) a1 += (double)WzT[(c1 * KT + k + 1) * 128 + co];
      if (c2 < 128) a2 += (double)WzT[(c2 * KT + k + 2) * 128 + co];
      if (c3 < 128) a3 += (double)WzT[(c3 * KT + k + 3) * 128 + co];
    }
    int cl = nbr[120];
    if (cl < 128) a0 += (double)WzT[(cl * KT + 120) * 128 + co];
    realy += (a0 + a1) + (a2 + a3);
  }
  realy -= bias[co];

  float zp = 0.f;
  if (t > 0) {
    zp = feat[(size_t)(b * 6 + (t - 1)) * 524288 + co * 4096 + hw];
    realy = 0.5 * realy + 0.5 * (double)zp;
  }

  // max over 128 channels
  double m = realy;
#pragma unroll
  for (int s = 1; s < 64; s <<= 1) m = fmax(m, __shfl_xor(m, s, 64));
  int wid = co >> 6;
  if ((co & 63) == 0) red[wid] = m;
  __syncthreads();
  double thr = fmax(red[0], red[1]);

  bool z = (realy == thr) && (realy > 0.0);
  feat[(size_t)(b * 6 + t) * 524288 + co * 4096 + hw] = z ? 1.0f : 0.0f;

  unsigned long long mb = __ballot(z);
  bool dif = ((z ? 1.0f : 0.0f) != zp);
  unsigned long long db = __ballot(dif);
  if ((co & 63) == 0) bal[wid] = mb;
  __syncthreads();

  if (co == 0) {
    unsigned long long b0 = bal[0], b1 = bal[1];
    int wi = 255;
    if (b0) wi = __ffsll((unsigned long long)b0) - 1;
    else if (b1) wi = 64 + __ffsll((unsigned long long)b1) - 1;
    widxCur[pix] = (unsigned int)wi;
  }
  if (z) atomicAdd(&counts[t * 128 + co], 1u);
  if ((co & 63) == 0 && db) atomicAdd(&chg[t], (unsigned int)__popcll(db));
}

// ---------------------------------------------------------------------------
// K4: bias update + changes[t]
// ---------------------------------------------------------------------------
__global__ __launch_bounds__(128) void k_fin(double* __restrict__ bias,
                                             float* __restrict__ outChanges,
                                             const unsigned int* __restrict__ counts,
                                             const unsigned int* __restrict__ chg,
                                             int t) {
  int co = threadIdx.x;
  double rate = (double)counts[t * 128 + co] * (1.0 / 32768.0);
  bias[co] += 0.05 * (rate - 1.0 / 128.0);
  if (co == 0) outChanges[t] = (float)((double)chg[t] * (1.0 / 8388608.0));
}

// ---------------------------------------------------------------------------
extern "C" void kernel_launch(void* const* d_in, const int* in_sizes, int n_in,
                              void* d_out, int out_size, void* d_ws, size_t ws_size,
                              hipStream_t stream) {
  const float* x = (const float*)d_in[0];
  const float* W = (const float*)d_in[1];
  float* out = (float*)d_out;

  char* ws = (char*)d_ws;
  float* WxT = (float*)ws;                               // 7,929,856 B
  float* WzT = (float*)(ws + 7929856);                   // 7,929,856 B
  double* base = (double*)(ws + 2 * 7929856);            // 33,554,432 B
  char* p = ws + 2 * 7929856 + 33554432;
  double* bias = (double*)p;           p += 1024;        // 128 f64
  unsigned int* counts = (unsigned int*)p; p += 6 * 128 * 4;  // 3072
  unsigned int* chg = (unsigned int*)p;    p += 256;
  unsigned int* widx0 = (unsigned int*)p;  p += TOTPIX * 4;
  unsigned int* widx1 = (unsigned int*)p;

  // zero bias + counts + chg (contiguous 4352 bytes)
  hipMemsetAsync(bias, 0, 4352, stream);

  k_wt<<<(2 * WPART + 255) / 256, 256, 0, stream>>>(W, WxT, WzT);
  k_conv<<<1024, 256, 0, stream>>>(x, WxT, base);

  float* feat = out + 6;
  for (int t = 0; t < 6; ++t) {
    unsigned int* wp = (t & 1) ? widx1 : widx0;
    unsigned int* wc = (t & 1) ? widx0 : widx1;
    k_step<<<TOTPIX, 128, 0, stream>>>(base, WzT, bias, wp, wc, feat, counts,
                                       chg, t);
    k_fin<<<1, 128, 0, stream>>>(bias, out, counts, chg, t);
  }
}

// Round 6
// 4254.759 us; speedup vs baseline: 1.2598x; 1.1171x over previous
//
#include <hip/hip_runtime.h>

typedef double d4 __attribute__((ext_vector_type(4)));

static constexpr int BN = 8;
static constexpr int CX = 128;   // x input channels
static constexpr int CO = 128;   // output channels
static constexpr int HH = 64;
static constexpr int WW = 64;
static constexpr int KT = 121;   // 11*11
static constexpr int NPIX = HH * WW;        // 4096
static constexpr int TOTPIX = BN * NPIX;    // 32768
static constexpr int WPART = CX * KT * CO;  // 1982464

// ---------------------------------------------------------------------------
// K1: transpose W [co][256][11][11] -> WxT [ci][k][co] (ci<128) and
//     WzT [cz][k][co] (input channels 128..255)
// ---------------------------------------------------------------------------
__global__ __launch_bounds__(256) void k_wt(const float* __restrict__ W,
                                            float* __restrict__ WxT,
                                            float* __restrict__ WzT) {
  int id = blockIdx.x * 256 + threadIdx.x;
  if (id >= 2 * WPART) return;
  int part = id / WPART;
  int r = id - part * WPART;
  int co = r & 127;
  int rk = r >> 7;          // ci*121 + k
  int k = rk % KT;
  int ci = rk / KT;
  float v = W[(co * 256 + part * 128 + ci) * KT + k];
  if (part) WzT[r] = v;
  else      WxT[r] = v;
}

// ---------------------------------------------------------------------------
// K2: base = conv(x, W[:, :128]) SAME pad 5, f64 MFMA (v_mfma_f64_16x16x4).
// GEMM view: C[co][pix] = sum_K W'[co][K] * X'[K][pix], K = (ci, ki, kj).
// Block tile: 1 b, 16 h, 16 w, 16 co; 4 waves, wave = 4 h rows (4 acc).
// K loop: ci outer (staged), taps padded 121->124, chunks of 4.
// D-LAYOUT CALIBRATION: two probe MFMAs measure, for every (lane, reg) slot,
// its co-offset (pr) and w-offset (pc). Epilogue addresses derive from the
// probes, so the kernel is correct under ANY bijective D fragment map
// (consecutive-row, reg-stride, or row/col-swapped variants).
// A/B staged with m/n = lane&15, k = lane>>4; a consistent k relabeling
// cancels in the reduction, so only the 16-wide digit (lane&15, verified
// family-wide on gfx950) is assumed.
// Grid: 8(co) * 4(w) * 4(h) * 8(b) = 1024 blocks = 4/CU. LDS 25,776 B.
// ---------------------------------------------------------------------------
__global__ __launch_bounds__(256, 4) void k_conv(const float* __restrict__ x,
                                                 const float* __restrict__ WxT,
                                                 double* __restrict__ base) {
  int blk = blockIdx.x;
  int cog = blk & 7;
  int wt  = (blk >> 3) & 3;
  int ht  = (blk >> 5) & 3;
  int b   = blk >> 7;
  int H0 = ht * 16, W0 = wt * 16, CO0 = cog * 16;

  int tid  = threadIdx.x;
  int lane = tid & 63;
  int wv   = tid >> 6;      // wave id -> h sub-tile (4 rows each)
  int lg   = lane >> 4;     // assumed k digit
  int lc   = lane & 15;     // 16-wide digit (co for A, w for B)

  // xs: [42][28] f64; rows 0..25, cols 0..25 hold the x window
  //     (rows H0-5..H0+20, cols W0-5..W0+20); rows 26..41 permanent zero
  //     apron for pad taps (row 26 + 4*wv + r <= 41).
  // wsl: [124][16] f64, wsl[k][co], k>=121 zeroed.
  // offtbl: ELEMENT offset into xs for tap k: ki*28+kj; k>=121 -> 26*28.
  __shared__ double xs[42 * 28];        // 9408 B
  __shared__ double wsl[124 * 16];      // 15872 B
  __shared__ unsigned offtbl[124];      // 496 B

  if (tid < 124) {
    unsigned off;
    if (tid < 121) {
      int ki = tid / 11, kj = tid - ki * 11;
      off = (unsigned)(ki * 28 + kj);
    } else {
      off = (unsigned)(26 * 28);        // zero apron
    }
    offtbl[tid] = off;
  }
  // zero-fill xs ONCE; per-ci staging only rewrites valid positions (the
  // valid set is block-constant), so zeros persist.
  for (int e = tid; e < 42 * 28; e += 256) xs[e] = 0.0;

  // --- D-layout probes (pure register math, no LDS dependence) ---
  d4 zz = {0., 0., 0., 0.};
  double amu  = (double)lc;                 // label = 16-wide digit value
  double bsel = (lg == 0) ? 1.0 : 0.0;      // one k-slice of ones
  d4 pr = __builtin_amdgcn_mfma_f64_16x16x4f64(amu, bsel, zz, 0, 0, 0);
  d4 pc = __builtin_amdgcn_mfma_f64_16x16x4f64(bsel, amu, zz, 0, 0, 0);

  d4 acc0 = {0., 0., 0., 0.};
  d4 acc1 = {0., 0., 0., 0.};
  d4 acc2 = {0., 0., 0., 0.};
  d4 acc3 = {0., 0., 0., 0.};

  unsigned xbase = (unsigned)(wv * 112 + lc);   // 4*wv rows of 28 + col lc

  for (int ci = 0; ci < CX; ++ci) {
    // --- stage x window rows 0..25, cols 0..25 (f32->f64 once) ---
    for (int e = tid; e < 26 * 28; e += 256) {
      int r = e / 28;
      int cc = e - r * 28;
      int gh = H0 - 5 + r;
      int gw = W0 - 5 + cc;
      if (cc < 26 && (unsigned)gh < 64u && (unsigned)gw < 64u)
        xs[e] = (double)x[((b * CX + ci) * HH + gh) * WW + gw];
    }
    // --- stage weights wsl[124][16] f64 (thread t: k=t>>1, 8 co each) ---
    if (tid < 248) {
      int k = tid >> 1;
      int half = (tid & 1) * 8;
      double2 w01, w23, w45, w67;
      if (k < 121) {
        const float* src = &WxT[(ci * KT + k) * 128 + CO0 + half];
        float4 f0 = *reinterpret_cast<const float4*>(src);
        float4 f1 = *reinterpret_cast<const float4*>(src + 4);
        w01.x = (double)f0.x; w01.y = (double)f0.y;
        w23.x = (double)f0.z; w23.y = (double)f0.w;
        w45.x = (double)f1.x; w45.y = (double)f1.y;
        w67.x = (double)f1.z; w67.y = (double)f1.w;
      } else {
        w01.x = 0; w01.y = 0; w23.x = 0; w23.y = 0;
        w45.x = 0; w45.y = 0; w67.x = 0; w67.y = 0;
      }
      double* dst = &wsl[k * 16 + half];
      *reinterpret_cast<double2*>(dst)     = w01;
      *reinterpret_cast<double2*>(dst + 2) = w23;
      *reinterpret_cast<double2*>(dst + 4) = w45;
      *reinterpret_cast<double2*>(dst + 6) = w67;
    }
    __syncthreads();

    // --- 31 K-chunks of 4 taps ---
#pragma unroll 31
    for (int c = 0; c < 31; ++c) {
      double a = wsl[(unsigned)(c * 64 + lg * 16 + lc)];   // wsl[4c+lg][lc]
      unsigned off = offtbl[(unsigned)(c * 4 + lg)];
      const double* bp = &xs[xbase + off];
      double b0 = bp[0];
      double b1 = bp[28];
      double b2 = bp[56];
      double b3 = bp[84];
      acc0 = __builtin_amdgcn_mfma_f64_16x16x4f64(a, b0, acc0, 0, 0, 0);
      acc1 = __builtin_amdgcn_mfma_f64_16x16x4f64(a, b1, acc1, 0, 0, 0);
      acc2 = __builtin_amdgcn_mfma_f64_16x16x4f64(a, b2, acc2, 0, 0, 0);
      acc3 = __builtin_amdgcn_mfma_f64_16x16x4f64(a, b3, acc3, 0, 0, 0);
    }
    __syncthreads();
  }

  // --- epilogue: slot (lane,i) holds conv(co = CO0+pr[i], w = W0+pc[i])
  //     at h = hbase + r for acc_r (h comes from the B row shift). ---
  int hbase = H0 + wv * 4;
#pragma unroll
  for (int i = 0; i < 4; ++i) {
    int co = CO0 + (int)pr[i];
    int wc = W0 + (int)pc[i];
    double* dst = &base[((b * CO + co) * HH + hbase) * WW + wc];
    dst[0 * WW] = acc0[i];
    dst[1 * WW] = acc1[i];
    dst[2 * WW] = acc2[i];
    dst[3 * WW] = acc3[i];
  }
}

// ---------------------------------------------------------------------------
// K3: one block per pixel (128 threads = 128 output channels).
// realy = base + lateral_gather - bias; t>0: 0.5*realy + 0.5*z_prev
// WTA over channels -> z, features, winner index, rate/change counts.
// ---------------------------------------------------------------------------
__global__ __launch_bounds__(128) void k_step(
    const double* __restrict__ base, const float* __restrict__ WzT,
    const double* __restrict__ bias, const unsigned int* __restrict__ widxPrev,
    unsigned int* __restrict__ widxCur, float* __restrict__ feat,
    unsigned int* __restrict__ counts, unsigned int* __restrict__ chg, int t) {
  int pix = blockIdx.x;
  int b  = pix >> 12;
  int hw = pix & 4095;
  int h = hw >> 6, w = hw & 63;
  int co = threadIdx.x;

  __shared__ int nbr[121];
  __shared__ double red[2];
  __shared__ unsigned long long bal[2];

  if (t > 0 && co < 121) {
    int ki = co / 11, kj = co - ki * 11;
    int nh = h + ki - 5, nw = w + kj - 5;
    int c = 255;
    if ((unsigned)nh < 64u && (unsigned)nw < 64u)
      c = (int)widxPrev[b * 4096 + nh * 64 + nw];
    nbr[co] = c;
  }
  __syncthreads();

  double realy = base[((b * 128 + co) * 64 + h) * 64 + w];
  if (t > 0) {
    // 4 partial sums break the serial f64 dependence chain
    double a0 = 0.0, a1 = 0.0, a2 = 0.0, a3 = 0.0;
#pragma unroll 2
    for (int k = 0; k < 120; k += 4) {
      int c0 = nbr[k], c1 = nbr[k + 1], c2 = nbr[k + 2], c3 = nbr[k + 3];
      if (c0 < 128) a0 += (double)WzT[(c0 * KT + k) * 128 + co];
      if (c1 < 128) a1 += (double)WzT[(c1 * KT + k + 1) * 128 + co];
      if (c2 < 128) a2 += (double)WzT[(c2 * KT + k + 2) * 128 + co];
      if (c3 < 128) a3 += (double)WzT[(c3 * KT + k + 3) * 128 + co];
    }
    int cl = nbr[120];
    if (cl < 128) a0 += (double)WzT[(cl * KT + 120) * 128 + co];
    realy += (a0 + a1) + (a2 + a3);
  }
  realy -= bias[co];

  float zp = 0.f;
  if (t > 0) {
    zp = feat[(size_t)(b * 6 + (t - 1)) * 524288 + co * 4096 + hw];
    realy = 0.5 * realy + 0.5 * (double)zp;
  }

  // max over 128 channels
  double m = realy;
#pragma unroll
  for (int s = 1; s < 64; s <<= 1) m = fmax(m, __shfl_xor(m, s, 64));
  int wid = co >> 6;
  if ((co & 63) == 0) red[wid] = m;
  __syncthreads();
  double thr = fmax(red[0], red[1]);

  bool z = (realy == thr) && (realy > 0.0);
  feat[(size_t)(b * 6 + t) * 524288 + co * 4096 + hw] = z ? 1.0f : 0.0f;

  unsigned long long mb = __ballot(z);
  bool dif = ((z ? 1.0f : 0.0f) != zp);
  unsigned long long db = __ballot(dif);
  if ((co & 63) == 0) bal[wid] = mb;
  __syncthreads();

  if (co == 0) {
    unsigned long long b0 = bal[0], b1 = bal[1];
    int wi = 255;
    if (b0) wi = __ffsll((unsigned long long)b0) - 1;
    else if (b1) wi = 64 + __ffsll((unsigned long long)b1) - 1;
    widxCur[pix] = (unsigned int)wi;
  }
  if (z) atomicAdd(&counts[t * 128 + co], 1u);
  if ((co & 63) == 0 && db) atomicAdd(&chg[t], (unsigned int)__popcll(db));
}

// ---------------------------------------------------------------------------
// K4: bias update + changes[t]
// ---------------------------------------------------------------------------
__global__ __launch_bounds__(128) void k_fin(double* __restrict__ bias,
                                             float* __restrict__ outChanges,
                                             const unsigned int* __restrict__ counts,
                                             const unsigned int* __restrict__ chg,
                                             int t) {
  int co = threadIdx.x;
  double rate = (double)counts[t * 128 + co] * (1.0 / 32768.0);
  bias[co] += 0.05 * (rate - 1.0 / 128.0);
  if (co == 0) outChanges[t] = (float)((double)chg[t] * (1.0 / 8388608.0));
}

// ---------------------------------------------------------------------------
extern "C" void kernel_launch(void* const* d_in, const int* in_sizes, int n_in,
                              void* d_out, int out_size, void* d_ws, size_t ws_size,
                              hipStream_t stream) {
  const float* x = (const float*)d_in[0];
  const float* W = (const float*)d_in[1];
  float* out = (float*)d_out;

  char* ws = (char*)d_ws;
  float* WxT = (float*)ws;                               // 7,929,856 B
  float* WzT = (float*)(ws + 7929856);                   // 7,929,856 B
  double* base = (double*)(ws + 2 * 7929856);            // 33,554,432 B
  char* p = ws + 2 * 7929856 + 33554432;
  double* bias = (double*)p;           p += 1024;        // 128 f64
  unsigned int* counts = (unsigned int*)p; p += 6 * 128 * 4;  // 3072
  unsigned int* chg = (unsigned int*)p;    p += 256;
  unsigned int* widx0 = (unsigned int*)p;  p += TOTPIX * 4;
  unsigned int* widx1 = (unsigned int*)p;

  // zero bias + counts + chg (contiguous 4352 bytes)
  hipMemsetAsync(bias, 0, 4352, stream);

  k_wt<<<(2 * WPART + 255) / 256, 256, 0, stream>>>(W, WxT, WzT);
  k_conv<<<1024, 256, 0, stream>>>(x, WxT, base);

  float* feat = out + 6;
  for (int t = 0; t < 6; ++t) {
    unsigned int* wp = (t & 1) ? widx1 : widx0;
    unsigned int* wc = (t & 1) ? widx0 : widx1;
    k_step<<<TOTPIX, 128, 0, stream>>>(base, WzT, bias, wp, wc, feat, counts,
                                       chg, t);
    k_fin<<<1, 128, 0, stream>>>(bias, out, counts, chg, t);
  }
}

// Round 7
// 4002.187 us; speedup vs baseline: 1.3393x; 1.0631x over previous
//
#include <hip/hip_runtime.h>

typedef double d4 __attribute__((ext_vector_type(4)));

static constexpr int BN = 8;
static constexpr int CX = 128;   // x input channels
static constexpr int CO = 128;   // output channels
static constexpr int HH = 64;
static constexpr int WW = 64;
static constexpr int KT = 121;   // 11*11
static constexpr int NPIX = HH * WW;        // 4096
static constexpr int TOTPIX = BN * NPIX;    // 32768

// ---------------------------------------------------------------------------
// K1: transpose W [co][256][11][11] -> WxT/WzT [ci][k][co].
// Block = (part, ci): 128 threads (one per co), loop over k.
// Reads: each thread streams 121 consecutive floats (L1-resident lines);
// writes: for each k, the 128 co-threads write one contiguous 512B run.
// ---------------------------------------------------------------------------
__global__ __launch_bounds__(128) void k_wt(const float* __restrict__ W,
                                            float* __restrict__ WxT,
                                            float* __restrict__ WzT) {
  int blk  = blockIdx.x;       // part*128 + ci
  int part = blk >> 7;
  int ci   = blk & 127;
  int co   = threadIdx.x;
  const float* src = &W[((co * 256) + part * 128 + ci) * KT];
  float* dst = (part ? WzT : WxT) + ci * KT * 128 + co;
#pragma unroll 11
  for (int k = 0; k < KT; ++k) dst[k * 128] = src[k];
}

// ---------------------------------------------------------------------------
// K2: base = conv(x, W[:, :128]) SAME pad 5, f64 MFMA (v_mfma_f64_16x16x4).
// Identical to the verified R5 kernel EXCEPT base is now PIXEL-MAJOR:
// base[b][hw][co] so k_step can read it coalesced.
// D-layout probe calibration retained (correct under any bijective D map).
// Grid: 8(co) * 4(w) * 4(h) * 8(b) = 1024 blocks = 4/CU. LDS 25,776 B.
// ---------------------------------------------------------------------------
__global__ __launch_bounds__(256, 4) void k_conv(const float* __restrict__ x,
                                                 const float* __restrict__ WxT,
                                                 double* __restrict__ base) {
  int blk = blockIdx.x;
  int cog = blk & 7;
  int wt  = (blk >> 3) & 3;
  int ht  = (blk >> 5) & 3;
  int b   = blk >> 7;
  int H0 = ht * 16, W0 = wt * 16, CO0 = cog * 16;

  int tid  = threadIdx.x;
  int lane = tid & 63;
  int wv   = tid >> 6;      // wave id -> h sub-tile (4 rows each)
  int lg   = lane >> 4;     // k digit
  int lc   = lane & 15;     // 16-wide digit (co for A, w for B)

  __shared__ double xs[42 * 28];        // 9408 B (rows 26..41 = zero apron)
  __shared__ double wsl[124 * 16];      // 15872 B, k>=121 zeroed
  __shared__ unsigned offtbl[124];      // element offsets into xs

  if (tid < 124) {
    unsigned off;
    if (tid < 121) {
      int ki = tid / 11, kj = tid - ki * 11;
      off = (unsigned)(ki * 28 + kj);
    } else {
      off = (unsigned)(26 * 28);        // zero apron
    }
    offtbl[tid] = off;
  }
  for (int e = tid; e < 42 * 28; e += 256) xs[e] = 0.0;

  // --- D-layout probes ---
  d4 zz = {0., 0., 0., 0.};
  double amu  = (double)lc;
  double bsel = (lg == 0) ? 1.0 : 0.0;
  d4 pr = __builtin_amdgcn_mfma_f64_16x16x4f64(amu, bsel, zz, 0, 0, 0);
  d4 pc = __builtin_amdgcn_mfma_f64_16x16x4f64(bsel, amu, zz, 0, 0, 0);

  d4 acc0 = {0., 0., 0., 0.};
  d4 acc1 = {0., 0., 0., 0.};
  d4 acc2 = {0., 0., 0., 0.};
  d4 acc3 = {0., 0., 0., 0.};

  unsigned xbase = (unsigned)(wv * 112 + lc);

  for (int ci = 0; ci < CX; ++ci) {
    for (int e = tid; e < 26 * 28; e += 256) {
      int r = e / 28;
      int cc = e - r * 28;
      int gh = H0 - 5 + r;
      int gw = W0 - 5 + cc;
      if (cc < 26 && (unsigned)gh < 64u && (unsigned)gw < 64u)
        xs[e] = (double)x[((b * CX + ci) * HH + gh) * WW + gw];
    }
    if (tid < 248) {
      int k = tid >> 1;
      int half = (tid & 1) * 8;
      double2 w01, w23, w45, w67;
      if (k < 121) {
        const float* src = &WxT[(ci * KT + k) * 128 + CO0 + half];
        float4 f0 = *reinterpret_cast<const float4*>(src);
        float4 f1 = *reinterpret_cast<const float4*>(src + 4);
        w01.x = (double)f0.x; w01.y = (double)f0.y;
        w23.x = (double)f0.z; w23.y = (double)f0.w;
        w45.x = (double)f1.x; w45.y = (double)f1.y;
        w67.x = (double)f1.z; w67.y = (double)f1.w;
      } else {
        w01.x = 0; w01.y = 0; w23.x = 0; w23.y = 0;
        w45.x = 0; w45.y = 0; w67.x = 0; w67.y = 0;
      }
      double* dst = &wsl[k * 16 + half];
      *reinterpret_cast<double2*>(dst)     = w01;
      *reinterpret_cast<double2*>(dst + 2) = w23;
      *reinterpret_cast<double2*>(dst + 4) = w45;
      *reinterpret_cast<double2*>(dst + 6) = w67;
    }
    __syncthreads();

#pragma unroll 31
    for (int c = 0; c < 31; ++c) {
      double a = wsl[(unsigned)(c * 64 + lg * 16 + lc)];
      unsigned off = offtbl[(unsigned)(c * 4 + lg)];
      const double* bp = &xs[xbase + off];
      double b0 = bp[0];
      double b1 = bp[28];
      double b2 = bp[56];
      double b3 = bp[84];
      acc0 = __builtin_amdgcn_mfma_f64_16x16x4f64(a, b0, acc0, 0, 0, 0);
      acc1 = __builtin_amdgcn_mfma_f64_16x16x4f64(a, b1, acc1, 0, 0, 0);
      acc2 = __builtin_amdgcn_mfma_f64_16x16x4f64(a, b2, acc2, 0, 0, 0);
      acc3 = __builtin_amdgcn_mfma_f64_16x16x4f64(a, b3, acc3, 0, 0, 0);
    }
    __syncthreads();
  }

  // --- epilogue (pixel-major base): slot (lane,i) = (co=CO0+pr[i], w=W0+pc[i])
  int hbase = H0 + wv * 4;
#pragma unroll
  for (int i = 0; i < 4; ++i) {
    int co = CO0 + (int)pr[i];
    int wc = W0 + (int)pc[i];
    double* dst = &base[((size_t)b * NPIX + hbase * 64 + wc) * 128 + co];
    dst[0 * 8192] = acc0[i];
    dst[1 * 8192] = acc1[i];
    dst[2 * 8192] = acc2[i];
    dst[3 * 8192] = acc3[i];
  }
}

// ---------------------------------------------------------------------------
// K3: one block per pixel (128 threads = 128 output channels).
// State is the per-pixel winner index (u8): z[co] = (widx==co).
// base read is coalesced (pixel-major). No feat traffic here.
// ---------------------------------------------------------------------------
__global__ __launch_bounds__(128) void k_step(
    const double* __restrict__ base, const float* __restrict__ WzT,
    const double* __restrict__ bias, const unsigned char* __restrict__ widxPrev,
    unsigned char* __restrict__ widxCur, unsigned int* __restrict__ counts,
    unsigned int* __restrict__ chg, int t) {
  int pix = blockIdx.x;
  int b  = pix >> 12;
  int hw = pix & 4095;
  int h = hw >> 6, w = hw & 63;
  int co = threadIdx.x;

  __shared__ int nbr[121];   // nbr[60] == widxPrev[pix] (center tap)
  __shared__ double red[2];
  __shared__ unsigned long long bal[2];

  if (t > 0) {
    if (co < 121) {
      int ki = co / 11, kj = co - ki * 11;
      int nh = h + ki - 5, nw = w + kj - 5;
      int c = 255;
      if ((unsigned)nh < 64u && (unsigned)nw < 64u)
        c = (int)widxPrev[b * 4096 + nh * 64 + nw];
      nbr[co] = c;
    }
    __syncthreads();
  }

  double realy = base[(size_t)pix * 128 + co];
  if (t > 0) {
    double a0 = 0.0, a1 = 0.0, a2 = 0.0, a3 = 0.0;
#pragma unroll 2
    for (int k = 0; k < 120; k += 4) {
      int c0 = nbr[k], c1 = nbr[k + 1], c2 = nbr[k + 2], c3 = nbr[k + 3];
      if (c0 < 128) a0 += (double)WzT[(c0 * KT + k) * 128 + co];
      if (c1 < 128) a1 += (double)WzT[(c1 * KT + k + 1) * 128 + co];
      if (c2 < 128) a2 += (double)WzT[(c2 * KT + k + 2) * 128 + co];
      if (c3 < 128) a3 += (double)WzT[(c3 * KT + k + 3) * 128 + co];
    }
    int cl = nbr[120];
    if (cl < 128) a0 += (double)WzT[(cl * KT + 120) * 128 + co];
    realy += (a0 + a1) + (a2 + a3);
  }
  realy -= bias[co];

  if (t > 0) {
    double zp = (nbr[60] == co) ? 1.0 : 0.0;
    realy = 0.5 * realy + 0.5 * zp;
  }

  // max over 128 channels
  double m = realy;
#pragma unroll
  for (int s = 1; s < 64; s <<= 1) m = fmax(m, __shfl_xor(m, s, 64));
  int wid = co >> 6;
  if ((co & 63) == 0) red[wid] = m;
  __syncthreads();
  double thr = fmax(red[0], red[1]);

  bool z = (realy == thr) && (realy > 0.0);
  unsigned long long mb = __ballot(z);
  if ((co & 63) == 0) bal[wid] = mb;
  __syncthreads();

  if (co == 0) {
    unsigned long long b0 = bal[0], b1 = bal[1];
    int wi = 255;
    if (b0) wi = __ffsll(b0) - 1;
    else if (b1) wi = 64 + __ffsll(b1) - 1;
    widxCur[pix] = (unsigned char)wi;
    if (wi < 128) atomicAdd(&counts[t * 128 + wi], 1u);
    int wp = (t > 0) ? nbr[60] : 255;
    if (wp != wi) {
      unsigned cnt = (unsigned)((wp != 255) + (wi != 255));
      atomicAdd(&chg[t], cnt);
    }
  }
}

// ---------------------------------------------------------------------------
// K4: bias update + changes[t]
// ---------------------------------------------------------------------------
__global__ __launch_bounds__(128) void k_fin(double* __restrict__ bias,
                                             float* __restrict__ outChanges,
                                             const unsigned int* __restrict__ counts,
                                             const unsigned int* __restrict__ chg,
                                             int t) {
  int co = threadIdx.x;
  double rate = (double)counts[t * 128 + co] * (1.0 / 32768.0);
  bias[co] += 0.05 * (rate - 1.0 / 128.0);
  if (co == 0) outChanges[t] = (float)((double)chg[t] * (1.0 / 8388608.0));
}

// ---------------------------------------------------------------------------
// K5: expand winner indices -> features [B][T][CO][H][W], fully coalesced.
// Thread = one float2 (2 consecutive hw). Total float2 = 6*8*128*2048.
// ---------------------------------------------------------------------------
__global__ __launch_bounds__(256) void k_feat(const unsigned char* __restrict__ widxA,
                                              float* __restrict__ featBase) {
  int idx = blockIdx.x * 256 + threadIdx.x;     // float2 index
  int hw2 = idx & 2047;
  int co  = (idx >> 11) & 127;
  int bt  = idx >> 18;          // b*6 + t
  int t = bt % 6, b = bt / 6;
  const unsigned char* wp = &widxA[(size_t)(t * BN + b) * 4096 + hw2 * 2];
  unsigned char w0 = wp[0], w1 = wp[1];
  float2 o;
  o.x = (w0 == co) ? 1.f : 0.f;
  o.y = (w1 == co) ? 1.f : 0.f;
  *reinterpret_cast<float2*>(&featBase[(size_t)idx * 2]) = o;
}

// ---------------------------------------------------------------------------
extern "C" void kernel_launch(void* const* d_in, const int* in_sizes, int n_in,
                              void* d_out, int out_size, void* d_ws, size_t ws_size,
                              hipStream_t stream) {
  const float* x = (const float*)d_in[0];
  const float* W = (const float*)d_in[1];
  float* out = (float*)d_out;

  char* ws = (char*)d_ws;
  float* WxT = (float*)ws;                               // 7,929,856 B
  float* WzT = (float*)(ws + 7929856);                   // 7,929,856 B
  double* base = (double*)(ws + 2 * 7929856);            // 33,554,432 B
  char* p = ws + 2 * 7929856 + 33554432;
  double* bias = (double*)p;               p += 1024;    // 128 f64
  unsigned int* counts = (unsigned int*)p; p += 6 * 128 * 4;  // 3072
  unsigned int* chg = (unsigned int*)p;    p += 256;
  unsigned char* widxA = (unsigned char*)p;              // 6 * 32768 u8

  // zero bias + counts + chg (contiguous 4352 bytes)
  hipMemsetAsync(bias, 0, 4352, stream);

  k_wt<<<256, 128, 0, stream>>>(W, WxT, WzT);
  k_conv<<<1024, 256, 0, stream>>>(x, WxT, base);

  for (int t = 0; t < 6; ++t) {
    unsigned char* wc = widxA + (size_t)t * TOTPIX;
    const unsigned char* wp = (t > 0) ? (widxA + (size_t)(t - 1) * TOTPIX)
                                      : widxA;  // unused at t=0
    k_step<<<TOTPIX, 128, 0, stream>>>(base, WzT, bias, wp, wc, counts, chg, t);
    k_fin<<<1, 128, 0, stream>>>(bias, out, counts, chg, t);
  }
  // features: 6*8*128*4096 floats = 12,582,912 float2 -> 49152 blocks
  k_feat<<<49152, 256, 0, stream>>>(widxA, out + 6);
}